// Round 11
// baseline (286.595 us; speedup 1.0000x reference)
//
#include <hip/hip_runtime.h>
#include <math.h>

#define QN 21760
#define MTOT 43520      // = 340 * 128
#define SZBQC 11141120  // MTOT*256

typedef __attribute__((ext_vector_type(8))) short bf16x8;
typedef __attribute__((ext_vector_type(4))) float f32x4;

__device__ inline ushort f2bf(float f) {
  union { float f; uint u; } v; v.f = f;
  return (ushort)((v.u + 0x7FFFu + ((v.u >> 16) & 1u)) >> 16);
}
__device__ inline uint pk2(float lo, float hi) { return (uint)f2bf(lo) | ((uint)f2bf(hi) << 16); }

__device__ inline void g2l(const ushort* g, ushort* l) {
  __builtin_amdgcn_global_load_lds(
      (const __attribute__((address_space(1))) void*)g,
      (__attribute__((address_space(3))) void*)l, 16, 0, 0);
}

// ---------------- weight prep ----------------
__global__ __launch_bounds__(256) void prep_weights(
    const float* __restrict__ Wv, const float* __restrict__ Wout,
    const float* __restrict__ Woff, const float* __restrict__ Wattn,
    const float* __restrict__ boff, const float* __restrict__ battn,
    ushort* __restrict__ wv_t, ushort* __restrict__ wout_t,
    ushort* __restrict__ wol_t, float* __restrict__ biasf) {
  int bidx = blockIdx.x, t = threadIdx.x;
  if (bidx < 256) {
    int idx = bidx * 256 + t; int n = idx >> 8, k = idx & 255;
    wv_t[idx] = f2bf(Wv[(size_t)k * 256 + n]);
  } else if (bidx < 512) {
    int idx = (bidx - 256) * 256 + t; int n = idx >> 8, k = idx & 255;
    wout_t[idx] = f2bf(Wout[(size_t)k * 256 + n]);
  } else {
    int idx = (bidx - 512) * 256 + t; int n = idx >> 8, k = idx & 255;
    float v = (n < 256) ? Woff[(size_t)k * 256 + n] : Wattn[(size_t)k * 128 + (n - 256)];
    wol_t[idx] = f2bf(v);
    if (idx < 384) biasf[idx] = (idx < 256) ? boff[idx] : battn[idx - 256];
  }
}

// ---- XOR-swizzled LDS tile: 128 rows x 32 ushort; 16B chunk c of row r
// lives at physical chunk c ^ ((r>>1)&3). Frag reads are conflict-free. ----

// ---------------- fused input GEMM (val + offlog), cast-in-loop ----------------
// DIAGNOSTIC SPLIT: launched twice with bx0=0 (grid 340x2, val panels) and
// bx0=2 (grid 340x3, offlog panels) so each shows separately in rocprof.
__global__ __launch_bounds__(256) void gemm_in(
    const float* __restrict__ value, const float* __restrict__ query,
    const ushort* __restrict__ Wv, const ushort* __restrict__ Wol,
    const float* __restrict__ bv, const float* __restrict__ bol,
    ushort* __restrict__ val_out, float* __restrict__ offlog, int bx0) {
  __shared__ ushort As[2][4096];
  __shared__ ushort Bs[2][4096];
  const int t = threadIdx.x, wave = t >> 6, lane = t & 63;
  const int bx = bx0 + blockIdx.y, bm = blockIdx.x * 128;
  const bool isVal = bx < 2;
  const float* A   = isVal ? value : query;
  const ushort* Bt = isVal ? (Wv + (size_t)bx * 128 * 256)
                           : (Wol + (size_t)(bx - 2) * 128 * 256);
  const int wm = (wave >> 1) * 64, wn = (wave & 1) * 64;
  const int l15 = lane & 15, l4 = lane >> 4;
  const int pc = l4 ^ ((l15 >> 1) & 3);              // frag-read physical chunk

  const int srow = lane >> 2;
  const int sch  = (lane & 3) ^ ((lane >> 3) & 3);
  const ushort* Bg = Bt + (size_t)(32 * wave + srow) * 256 + sch * 8;
  ushort* lb[2] = { &Bs[0][(32 * wave) * 32], &Bs[1][(32 * wave) * 32] };

  f32x4 acc[4][4];
#pragma unroll
  for (int i = 0; i < 4; ++i)
#pragma unroll
    for (int j = 0; j < 4; ++j) acc[i][j] = (f32x4){0.f, 0.f, 0.f, 0.f};

  int arow[4], apart[4];
#pragma unroll
  for (int i = 0; i < 4; ++i) {
    int c = t + i * 256; arow[i] = c >> 3; apart[i] = c & 7;
  }

  {
    float4 pa[4];
#pragma unroll
    for (int i = 0; i < 4; ++i)
      pa[i] = *(const float4*)&A[(size_t)(bm + arow[i]) * 256 + apart[i] * 4];
    g2l(Bg, lb[0]); g2l(Bg + 16 * 256, lb[0] + 16 * 32);
#pragma unroll
    for (int i = 0; i < 4; ++i) {
      int pc16 = (apart[i] >> 1) ^ ((arow[i] >> 1) & 3);
      ushort4 hv = { f2bf(pa[i].x), f2bf(pa[i].y), f2bf(pa[i].z), f2bf(pa[i].w) };
      *(ushort4*)&As[0][arow[i] * 32 + pc16 * 8 + (apart[i] & 1) * 4] = hv;
    }
  }

  for (int k = 0; k < 8; ++k) {
    __syncthreads();
    const int cur = k & 1, nxt = cur ^ 1;
    float4 pa[4];
    if (k < 7) {
      int k1 = (k + 1) * 32;
#pragma unroll
      for (int i = 0; i < 4; ++i)
        pa[i] = *(const float4*)&A[(size_t)(bm + arow[i]) * 256 + k1 + apart[i] * 4];
      g2l(Bg + k1, lb[nxt]); g2l(Bg + 16 * 256 + k1, lb[nxt] + 16 * 32);
    }
    bf16x8 af[4], bfr[4];
#pragma unroll
    for (int mi = 0; mi < 4; ++mi)
      af[mi] = *(const bf16x8*)&As[cur][(wm + mi * 16 + l15) * 32 + pc * 8];
#pragma unroll
    for (int ni = 0; ni < 4; ++ni)
      bfr[ni] = *(const bf16x8*)&Bs[cur][(wn + ni * 16 + l15) * 32 + pc * 8];
#pragma unroll
    for (int mi = 0; mi < 4; ++mi)
#pragma unroll
      for (int ni = 0; ni < 4; ++ni)
        acc[mi][ni] = __builtin_amdgcn_mfma_f32_16x16x32_bf16(af[mi], bfr[ni], acc[mi][ni], 0, 0, 0);
    if (k < 7) {
#pragma unroll
      for (int i = 0; i < 4; ++i) {
        int pc16 = (apart[i] >> 1) ^ ((arow[i] >> 1) & 3);
        ushort4 hv = { f2bf(pa[i].x), f2bf(pa[i].y), f2bf(pa[i].z), f2bf(pa[i].w) };
        *(ushort4*)&As[nxt][arow[i] * 32 + pc16 * 8 + (apart[i] & 1) * 4] = hv;
      }
    }
  }

  if (isVal) {
    _Float16* vo = (_Float16*)val_out;
#pragma unroll
    for (int mi = 0; mi < 4; ++mi)
#pragma unroll
      for (int ni = 0; ni < 4; ++ni) {
        int col = bx * 128 + wn + ni * 16 + l15;
        float bb = bv[col];
        int hh = col >> 5, c = col & 31;
#pragma unroll
        for (int r = 0; r < 4; ++r) {
          int row = bm + wm + mi * 16 + l4 * 4 + r;
          int b = (row >= QN) ? 1 : 0;
          int vpos = row - b * QN;
          vo[((size_t)(b * 8 + hh) * QN + vpos) * 32 + c] = (_Float16)(acc[mi][ni][r] + bb);
        }
      }
  } else {
#pragma unroll
    for (int mi = 0; mi < 4; ++mi)
#pragma unroll
      for (int ni = 0; ni < 4; ++ni) {
        int col = (bx - 2) * 128 + wn + ni * 16 + l15;
        float bb = bol[col];
#pragma unroll
        for (int r = 0; r < 4; ++r) {
          int row = bm + wm + mi * 16 + l4 * 4 + r;
          offlog[(size_t)row * 384 + col] = acc[mi][ni][r] + bb;
        }
      }
  }
}

// ---------------- output GEMM (A bf16), dbuf, all-g2l, swizzled ----------------
__global__ __launch_bounds__(256) void gemm_out(
    const ushort* __restrict__ A, const ushort* __restrict__ Bt,
    const float* __restrict__ bias, float* __restrict__ C) {
  __shared__ ushort As[2][4096];
  __shared__ ushort Bs[2][4096];
  const int t = threadIdx.x, wave = t >> 6, lane = t & 63;
  const int bm = blockIdx.x * 128, bn = blockIdx.y * 128;
  const int wm = (wave >> 1) * 64, wn = (wave & 1) * 64;
  const int l15 = lane & 15, l4 = lane >> 4;
  const int pc = l4 ^ ((l15 >> 1) & 3);

  const int srow = lane >> 2;
  const int sch  = (lane & 3) ^ ((lane >> 3) & 3);
  const ushort* Ag = A + (size_t)(bm + 32 * wave + srow) * 256 + sch * 8;
  const ushort* Bg = Bt + (size_t)(bn + 32 * wave + srow) * 256 + sch * 8;
  ushort* la[2] = { &As[0][(32 * wave) * 32], &As[1][(32 * wave) * 32] };
  ushort* lb[2] = { &Bs[0][(32 * wave) * 32], &Bs[1][(32 * wave) * 32] };

  f32x4 acc[4][4];
#pragma unroll
  for (int i = 0; i < 4; ++i)
#pragma unroll
    for (int j = 0; j < 4; ++j) acc[i][j] = (f32x4){0.f, 0.f, 0.f, 0.f};

  g2l(Ag, la[0]); g2l(Ag + 16 * 256, la[0] + 16 * 32);
  g2l(Bg, lb[0]); g2l(Bg + 16 * 256, lb[0] + 16 * 32);

  for (int k = 0; k < 8; ++k) {
    __syncthreads();
    const int cur = k & 1, nxt = cur ^ 1;
    if (k < 7) {
      int k1 = (k + 1) * 32;
      g2l(Ag + k1, la[nxt]); g2l(Ag + 16 * 256 + k1, la[nxt] + 16 * 32);
      g2l(Bg + k1, lb[nxt]); g2l(Bg + 16 * 256 + k1, lb[nxt] + 16 * 32);
    }
    bf16x8 af[4], bfr[4];
#pragma unroll
    for (int mi = 0; mi < 4; ++mi)
      af[mi] = *(const bf16x8*)&As[cur][(wm + mi * 16 + l15) * 32 + pc * 8];
#pragma unroll
    for (int ni = 0; ni < 4; ++ni)
      bfr[ni] = *(const bf16x8*)&Bs[cur][(wn + ni * 16 + l15) * 32 + pc * 8];
#pragma unroll
    for (int mi = 0; mi < 4; ++mi)
#pragma unroll
      for (int ni = 0; ni < 4; ++ni)
        acc[mi][ni] = __builtin_amdgcn_mfma_f32_16x16x32_bf16(af[mi], bfr[ni], acc[mi][ni], 0, 0, 0);
  }

#pragma unroll
  for (int mi = 0; mi < 4; ++mi)
#pragma unroll
    for (int ni = 0; ni < 4; ++ni) {
      int col = bn + wn + ni * 16 + l15;
      float bb = bias[col];
#pragma unroll
      for (int r = 0; r < 4; ++r) {
        int row = bm + wm + mi * 16 + l4 * 4 + r;
        C[(size_t)row * 256 + col] = acc[mi][ni][r] + bb;
      }
    }
}

// ---------------- deformable sampling ----------------
// v7 body (8-lane x-pair groups + point-pair ownership), unchanged from r9.
// DIAGNOSTIC SPLIT: launched 4x with vb0 = {0,2720,5440,8160}, 2720 blocks
// each, so msda quarters (~20 us) stop monopolizing the rocprof top-5.
__device__ inline void fmah(float* a, uint4 u, float wv) {
  union { uint4 u; _Float16 h[8]; } c; c.u = u;
#pragma unroll
  for (int i = 0; i < 8; ++i) a[i] = fmaf((float)c.h[i], wv, a[i]);
}

__global__ __launch_bounds__(256) void msda_sample(
    const ushort* __restrict__ val, const float* __restrict__ offlog,
    const float* __restrict__ ref, ushort* __restrict__ interm, int vb0) {
  int vb  = vb0 + blockIdx.x;
  int h   = vb & 7;
  int z   = vb >> 3;                       // 0..1359
  int s   = threadIdx.x & 7;               // sub-lane in 8-lane group
  int o   = s & 3;                         // owned level
  int pp  = s >> 2;                        // owned point-pair (pts 2pp, 2pp+1)
  bool xs = s >= 4;                        // consumed x-side
  int bq  = z * 32 + (threadIdx.x >> 3);   // 1360*32 = 43520
  int b   = (bq >= QN) ? 1 : 0;
  const ushort* vbl = val + (size_t)((uint)(b * 8 + h) * (uint)QN) * 32u + (uint)(s * 8);

  // ---- softmax: lane owns 2 logits (level o, points 2pp,2pp+1) ----
  const float* lgp = offlog + (size_t)bq * 384 + 256 + h * 16;
  float2 lg = *(const float2*)(lgp + o * 4 + pp * 2);
  float m = fmaxf(lg.x, lg.y);
  m = fmaxf(m, __shfl_xor(m, 1, 64));
  m = fmaxf(m, __shfl_xor(m, 2, 64));
  m = fmaxf(m, __shfl_xor(m, 4, 64));
  float e0 = __expf(lg.x - m), e1 = __expf(lg.y - m);
  float ssum = e0 + e1;
  ssum += __shfl_xor(ssum, 1, 64);
  ssum += __shfl_xor(ssum, 2, 64);
  ssum += __shfl_xor(ssum, 4, 64);
  float inv = __builtin_amdgcn_rcpf(ssum);
  float aw0 = e0 * inv, aw1 = e1 * inv;

  // ---- owned geometry: level o, points 2pp and 2pp+1 ----
  const int  Wl  = 128 >> o;                       // 128,64,32,16
  const uint t16 = 65536u >> (o + o);
  const int  lst = (int)((65536u - t16) / 3u);     // 0,16384,20480,21504
  const float fW = (float)Wl;
  const float* offp = offlog + (size_t)bq * 384 + h * 32;
  float4 f0 = *(const float4*)(offp + o * 8 + pp * 4);   // ox,oy for 2 pts
  float2 rf = *(const float2*)(ref + (size_t)bq * 8 + o * 2);
  const float xb = rf.x * fW - 0.5f;
  const float yb = rf.y * fW - 0.5f;
  float ox[2] = { f0.x, f0.z };
  float oy[2] = { f0.y, f0.w };
  float awq[2] = { aw0, aw1 };

  uint  pA0[2], pA1[2];
  float pW0[2], pW1[2], pY0[2], pY1[2];
#pragma unroll
  for (int q = 0; q < 2; ++q) {
    float x = xb + ox[q], y = yb + oy[q];
    float x0f = floorf(x), y0f = floorf(y);
    float fx = x - x0f, fy = y - y0f;
    int x0 = (int)x0f, y0 = (int)y0f;
    float a = awq[q];
    // masked corner weights (reference semantics)
    float wx0 = ((uint)x0       < (uint)Wl) ? (1.f - fx) : 0.f;
    float wx1 = ((uint)(x0 + 1) < (uint)Wl) ? fx         : 0.f;
    pY0[q] = (((uint)y0       < (uint)Wl) ? (1.f - fy) : 0.f) * a;
    pY1[q] = (((uint)(y0 + 1) < (uint)Wl) ? fy         : 0.f) * a;
    // clamped corner indices (reference semantics)
    int xc0 = min(max(x0, 0), Wl - 1);
    int xc1 = min(max(x0 + 1, 0), Wl - 1);
    int yc0 = min(max(y0, 0), Wl - 1);
    int yc1 = min(max(y0 + 1, 0), Wl - 1);
    // aligned x-pair base; consumer lane xside reads pixel xbase+xside
    int xbase = min(max(x0, 0), Wl - 2);
    // per-x-side lane weights: sum of reference corner weights on that pixel
    pW0[q] = ((xbase     == xc0) ? wx0 : 0.f) + ((xbase     == xc1) ? wx1 : 0.f);
    pW1[q] = ((xbase + 1 == xc0) ? wx0 : 0.f) + ((xbase + 1 == xc1) ? wx1 : 0.f);
    pA0[q] = (uint)((lst + yc0 * Wl + xbase) * 32);   // elem offset, row y0
    pA1[q] = (uint)((lst + yc1 * Wl + xbase) * 32);   // elem offset, row y1
  }

  float acc[8];
#pragma unroll
  for (int i = 0; i < 8; ++i) acc[i] = 0.f;

  const int gb = (threadIdx.x & 63) & ~7;            // group base lane

  uint  bA0[2], bA1[2];
  float bW[2], bY0[2], bY1[2];
  uint4 u0[2], u1[2];

  // point j: level l=j>>2, point p=j&3 -> owner lane gb|((p>>1)<<2)|l,
  // owner array slot p&1 (all compile-time under full unroll).
#define MSDA_BCAST(J, S) do {                                   \
    const int l_ = (J) >> 2, p_ = (J) & 3;                      \
    const int src_ = gb | ((p_ >> 1) << 2) | l_;                \
    const int q_ = p_ & 1;                                      \
    bA0[S] = (uint)__shfl((int)pA0[q_], src_, 64);              \
    bA1[S] = (uint)__shfl((int)pA1[q_], src_, 64);              \
    float w0_ = __shfl(pW0[q_], src_, 64);                      \
    float w1_ = __shfl(pW1[q_], src_, 64);                      \
    bW[S]  = xs ? w1_ : w0_;                                    \
    bY0[S] = __shfl(pY0[q_], src_, 64);                         \
    bY1[S] = __shfl(pY1[q_], src_, 64);                         \
  } while (0)
#define MSDA_LOAD(S) do {                                       \
    u0[S] = *(const uint4*)(vbl + bA0[S]);                      \
    u1[S] = *(const uint4*)(vbl + bA1[S]);                      \
  } while (0)

  MSDA_BCAST(0, 0);
  MSDA_LOAD(0);
#pragma unroll
  for (int j = 0; j < 16; ++j) {
    const int cur = j & 1, nxt = cur ^ 1;
    if (j < 15) { MSDA_BCAST(j + 1, nxt); MSDA_LOAD(nxt); }
    fmah(acc, u0[cur], bW[cur] * bY0[cur]);
    fmah(acc, u1[cur], bW[cur] * bY1[cur]);
  }
#undef MSDA_BCAST
#undef MSDA_LOAD

  // merge x-sides (lanes s and s^4 hold the two halves of the same chq)
#pragma unroll
  for (int i = 0; i < 8; ++i) acc[i] += __shfl_xor(acc[i], 4, 64);

  // each lane stores 8B: xside0 -> channels [chq*8, +4), xside1 -> +4..8
  uint2 ov;
  if (!xs) { ov.x = pk2(acc[0], acc[1]); ov.y = pk2(acc[2], acc[3]); }
  else     { ov.x = pk2(acc[4], acc[5]); ov.y = pk2(acc[6], acc[7]); }
  *(uint2*)(interm + (size_t)bq * 256 + h * 32 + (s & 3) * 8 + (xs ? 4 : 0)) = ov;
}

extern "C" void kernel_launch(void* const* d_in, const int* in_sizes, int n_in,
                              void* d_out, int out_size, void* d_ws, size_t ws_size,
                              hipStream_t stream) {
  const float* query = (const float*)d_in[0];
  const float* value = (const float*)d_in[1];
  const float* ref   = (const float*)d_in[2];
  const float* W_off  = (const float*)d_in[4];
  const float* b_off  = (const float*)d_in[5];
  const float* W_attn = (const float*)d_in[6];
  const float* b_attn = (const float*)d_in[7];
  const float* W_v    = (const float*)d_in[8];
  const float* b_v    = (const float*)d_in[9];
  const float* W_out  = (const float*)d_in[10];
  const float* b_out  = (const float*)d_in[11];
  float* out = (float*)d_out;

  // ---- workspace (byte offsets, 256-aligned) ----
  char* wsb = (char*)d_ws;
  ushort* ws_wv     = (ushort*)(wsb + 0);          // 131072 B
  ushort* ws_wol    = (ushort*)(wsb + 131072);     // 196608 B
  ushort* ws_wout   = (ushort*)(wsb + 327680);     // 131072 B
  float*  ws_biasf  = (float*)(wsb + 458752);      // 4096 B
  ushort* ws_val    = (ushort*)(wsb + 462848);     // 22282240 B fp16 head-split
  ushort* ws_interm = (ushort*)(wsb + 22745088);   // 22282240 B bf16 (M,256)
  float*  ws_offlog = (float*)(wsb + 45027328);    // 66846720 B f32 (M,384)
  size_t need = (size_t)45027328 + 66846720;       // ~112 MB
  if (ws_size < need) return;

  dim3 blk(256);
  prep_weights<<<dim3(896), blk, 0, stream>>>(W_v, W_out, W_off, W_attn, b_off, b_attn,
                                              ws_wv, ws_wout, ws_wol, ws_biasf);
  // diagnostic split: val panels and offlog panels as separate dispatches
  gemm_in<<<dim3(340, 2), blk, 0, stream>>>(value, query, ws_wv, ws_wol, b_v, ws_biasf,
                                            ws_val, ws_offlog, 0);
  gemm_in<<<dim3(340, 3), blk, 0, stream>>>(value, query, ws_wv, ws_wol, b_v, ws_biasf,
                                            ws_val, ws_offlog, 2);
  // diagnostic split: msda in 4 quarters
  msda_sample<<<dim3(2720), blk, 0, stream>>>(ws_val, ws_offlog, ref, ws_interm, 0);
  msda_sample<<<dim3(2720), blk, 0, stream>>>(ws_val, ws_offlog, ref, ws_interm, 2720);
  msda_sample<<<dim3(2720), blk, 0, stream>>>(ws_val, ws_offlog, ref, ws_interm, 5440);
  msda_sample<<<dim3(2720), blk, 0, stream>>>(ws_val, ws_offlog, ref, ws_interm, 8160);
  gemm_out<<<dim3(340, 2), blk, 0, stream>>>(ws_interm, ws_wout, b_out, out);
}

// Round 12
// 281.296 us; speedup vs baseline: 1.0188x; 1.0188x over previous
//
#include <hip/hip_runtime.h>
#include <math.h>

#define QN 21760
#define MTOT 43520      // = 340 * 128
#define SZBQC 11141120  // MTOT*256

typedef __attribute__((ext_vector_type(8))) short bf16x8;
typedef __attribute__((ext_vector_type(4))) float f32x4;

__device__ inline ushort f2bf(float f) {
  union { float f; uint u; } v; v.f = f;
  return (ushort)((v.u + 0x7FFFu + ((v.u >> 16) & 1u)) >> 16);
}
__device__ inline uint pk2(float lo, float hi) { return (uint)f2bf(lo) | ((uint)f2bf(hi) << 16); }

__device__ inline void g2l(const ushort* g, ushort* l) {
  __builtin_amdgcn_global_load_lds(
      (const __attribute__((address_space(1))) void*)g,
      (__attribute__((address_space(3))) void*)l, 16, 0, 0);
}

// ---------------- weight prep ----------------
__global__ __launch_bounds__(256) void prep_weights(
    const float* __restrict__ Wv, const float* __restrict__ Wout,
    const float* __restrict__ Woff, const float* __restrict__ Wattn,
    const float* __restrict__ boff, const float* __restrict__ battn,
    ushort* __restrict__ wv_t, ushort* __restrict__ wout_t,
    ushort* __restrict__ wol_t, float* __restrict__ biasf) {
  int bidx = blockIdx.x, t = threadIdx.x;
  if (bidx < 256) {
    int idx = bidx * 256 + t; int n = idx >> 8, k = idx & 255;
    wv_t[idx] = f2bf(Wv[(size_t)k * 256 + n]);
  } else if (bidx < 512) {
    int idx = (bidx - 256) * 256 + t; int n = idx >> 8, k = idx & 255;
    wout_t[idx] = f2bf(Wout[(size_t)k * 256 + n]);
  } else {
    int idx = (bidx - 512) * 256 + t; int n = idx >> 8, k = idx & 255;
    float v = (n < 256) ? Woff[(size_t)k * 256 + n] : Wattn[(size_t)k * 128 + (n - 256)];
    wol_t[idx] = f2bf(v);
    if (idx < 384) biasf[idx] = (idx < 256) ? boff[idx] : battn[idx - 256];
  }
}

// ---- XOR-swizzled LDS tile: 128 rows x 32 ushort; 16B chunk c of row r
// lives at physical chunk c ^ ((r>>1)&3). Frag reads are conflict-free. ----

// ---------------- fused input GEMM — counted-vmcnt, raw-barrier, 3-buf ----------
// Ledger (per wave, full unroll):
//   prologue: issue B0(2) B1(2) g2l, A0(4) A1(4) reg loads; compiler waits A0
//   (vmcnt<=4) -> B0,B1 landed; dsw A0 -> As[0]; lgkmcnt(0).
//   iter k: vmcnt(6) [outstanding <= B(k+1)2 + A(k+1)4; B(k) landed] ->
//   s_barrier -> issue B(k+2) g2l [WAR-safe: buf (k+2)%3 last read iter k-1,
//   done before barrier(k)] -> ds_read frags(k) -> 16 MFMA -> cast+dsw A(k+1)
//   [compiler waits A(k+1) regs] -> issue A(k+2) into freed reg set ->
//   lgkmcnt(0). Never vmcnt(0) in-loop (k=7 exact-drain only).
__global__ __launch_bounds__(256) void gemm_in(
    const float* __restrict__ value, const float* __restrict__ query,
    const ushort* __restrict__ Wv, const ushort* __restrict__ Wol,
    const float* __restrict__ bv, const float* __restrict__ bol,
    ushort* __restrict__ val_out, float* __restrict__ offlog, int bx0) {
  __shared__ ushort As[3][4096];
  __shared__ ushort Bs[3][4096];
  const int t = threadIdx.x, wave = t >> 6, lane = t & 63;
  const int bx = bx0 + blockIdx.y, bm = blockIdx.x * 128;
  const bool isVal = bx < 2;
  const float* A   = isVal ? value : query;
  const ushort* Bt = isVal ? (Wv + (size_t)bx * 128 * 256)
                           : (Wol + (size_t)(bx - 2) * 128 * 256);
  const int wm = (wave >> 1) * 64, wn = (wave & 1) * 64;
  const int l15 = lane & 15, l4 = lane >> 4;
  const int pc = l4 ^ ((l15 >> 1) & 3);              // frag-read physical chunk

  const int srow = lane >> 2;
  const int sch  = (lane & 3) ^ ((lane >> 3) & 3);
  const ushort* Bg = Bt + (size_t)(32 * wave + srow) * 256 + sch * 8;
  ushort* lb[3] = { &Bs[0][(32 * wave) * 32], &Bs[1][(32 * wave) * 32],
                    &Bs[2][(32 * wave) * 32] };

  f32x4 acc[4][4];
#pragma unroll
  for (int i = 0; i < 4; ++i)
#pragma unroll
    for (int j = 0; j < 4; ++j) acc[i][j] = (f32x4){0.f, 0.f, 0.f, 0.f};

  int arow[4], apart[4];
#pragma unroll
  for (int i = 0; i < 4; ++i) {
    int c = t + i * 256; arow[i] = c >> 3; apart[i] = c & 7;
  }

#define GIN_LOADA(dst, koff) do {                                          \
    _Pragma("unroll")                                                      \
    for (int i_ = 0; i_ < 4; ++i_)                                         \
      dst[i_] = *(const float4*)&A[(size_t)(bm + arow[i_]) * 256 + (koff) + apart[i_] * 4]; \
  } while (0)
#define GIN_STOREA(buf, src) do {                                          \
    _Pragma("unroll")                                                      \
    for (int i_ = 0; i_ < 4; ++i_) {                                       \
      int pc16_ = (apart[i_] >> 1) ^ ((arow[i_] >> 1) & 3);                \
      ushort4 hv_ = { f2bf(src[i_].x), f2bf(src[i_].y),                    \
                      f2bf(src[i_].z), f2bf(src[i_].w) };                  \
      *(ushort4*)&As[buf][arow[i_] * 32 + pc16_ * 8 + (apart[i_] & 1) * 4] = hv_; \
    }                                                                      \
  } while (0)

  float4 paA[4], paB[4];
  // prologue
  g2l(Bg, lb[0]);       g2l(Bg + 16 * 256, lb[0] + 16 * 32);        // B0
  g2l(Bg + 32, lb[1]);  g2l(Bg + 16 * 256 + 32, lb[1] + 16 * 32);   // B1
  GIN_LOADA(paA, 0);    // A0
  GIN_LOADA(paB, 32);   // A1
  GIN_STOREA(0, paA);   // compiler waits A0 -> forces B0,B1 landed
  asm volatile("s_waitcnt lgkmcnt(0)" ::: "memory");

#pragma unroll
  for (int k = 0; k < 8; ++k) {
    const int cb = k % 3;
    const int sb = (k + 2) % 3;
    if (k < 7) { asm volatile("s_waitcnt vmcnt(6)" ::: "memory"); }
    else       { asm volatile("s_waitcnt vmcnt(0)" ::: "memory"); }
    __builtin_amdgcn_sched_barrier(0);
    __builtin_amdgcn_s_barrier();
    __builtin_amdgcn_sched_barrier(0);
    if (k + 2 <= 7) {
      int k2 = (k + 2) * 32;
      g2l(Bg + k2, lb[sb]); g2l(Bg + 16 * 256 + k2, lb[sb] + 16 * 32);
    }
    bf16x8 af[4], bfr[4];
#pragma unroll
    for (int mi = 0; mi < 4; ++mi)
      af[mi] = *(const bf16x8*)&As[cb][(wm + mi * 16 + l15) * 32 + pc * 8];
#pragma unroll
    for (int ni = 0; ni < 4; ++ni)
      bfr[ni] = *(const bf16x8*)&Bs[cb][(wn + ni * 16 + l15) * 32 + pc * 8];
#pragma unroll
    for (int mi = 0; mi < 4; ++mi)
#pragma unroll
      for (int ni = 0; ni < 4; ++ni)
        acc[mi][ni] = __builtin_amdgcn_mfma_f32_16x16x32_bf16(af[mi], bfr[ni], acc[mi][ni], 0, 0, 0);
    if (k < 7) {
      const int wbuf = (k + 1) % 3;
      if ((k & 1) == 0) {
        GIN_STOREA(wbuf, paB);                       // A(k+1) from set1
        if (k + 2 <= 7) GIN_LOADA(paA, (k + 2) * 32);
      } else {
        GIN_STOREA(wbuf, paA);                       // A(k+1) from set0
        if (k + 2 <= 7) GIN_LOADA(paB, (k + 2) * 32);
      }
    }
    asm volatile("s_waitcnt lgkmcnt(0)" ::: "memory");
  }
#undef GIN_LOADA
#undef GIN_STOREA

  if (isVal) {
    _Float16* vo = (_Float16*)val_out;
#pragma unroll
    for (int mi = 0; mi < 4; ++mi)
#pragma unroll
      for (int ni = 0; ni < 4; ++ni) {
        int col = bx * 128 + wn + ni * 16 + l15;
        float bb = bv[col];
        int hh = col >> 5, c = col & 31;
#pragma unroll
        for (int r = 0; r < 4; ++r) {
          int row = bm + wm + mi * 16 + l4 * 4 + r;
          int b = (row >= QN) ? 1 : 0;
          int vpos = row - b * QN;
          vo[((size_t)(b * 8 + hh) * QN + vpos) * 32 + c] = (_Float16)(acc[mi][ni][r] + bb);
        }
      }
  } else {
#pragma unroll
    for (int mi = 0; mi < 4; ++mi)
#pragma unroll
      for (int ni = 0; ni < 4; ++ni) {
        int col = (bx - 2) * 128 + wn + ni * 16 + l15;
        float bb = bol[col];
#pragma unroll
        for (int r = 0; r < 4; ++r) {
          int row = bm + wm + mi * 16 + l4 * 4 + r;
          offlog[(size_t)row * 384 + col] = acc[mi][ni][r] + bb;
        }
      }
  }
}

// ---------------- output GEMM — counted-vmcnt, raw-barrier, 3-buf, all-g2l ----
// Ledger: prologue issues stage0(4) stage1(4). iter k: vmcnt(4) [outstanding
// = stage(k+1)'s 4; stage(k) landed] -> s_barrier -> issue stage(k+2)
// [WAR-safe] -> ds_read frags(k) -> MFMA. k=7 waits vmcnt(0) (exact drain).
__global__ __launch_bounds__(256) void gemm_out(
    const ushort* __restrict__ A, const ushort* __restrict__ Bt,
    const float* __restrict__ bias, float* __restrict__ C) {
  __shared__ ushort As[3][4096];
  __shared__ ushort Bs[3][4096];
  const int t = threadIdx.x, wave = t >> 6, lane = t & 63;
  const int bm = blockIdx.x * 128, bn = blockIdx.y * 128;
  const int wm = (wave >> 1) * 64, wn = (wave & 1) * 64;
  const int l15 = lane & 15, l4 = lane >> 4;
  const int pc = l4 ^ ((l15 >> 1) & 3);

  const int srow = lane >> 2;
  const int sch  = (lane & 3) ^ ((lane >> 3) & 3);
  const ushort* Ag = A + (size_t)(bm + 32 * wave + srow) * 256 + sch * 8;
  const ushort* Bg = Bt + (size_t)(bn + 32 * wave + srow) * 256 + sch * 8;
  ushort* la[3] = { &As[0][(32 * wave) * 32], &As[1][(32 * wave) * 32],
                    &As[2][(32 * wave) * 32] };
  ushort* lb[3] = { &Bs[0][(32 * wave) * 32], &Bs[1][(32 * wave) * 32],
                    &Bs[2][(32 * wave) * 32] };

  f32x4 acc[4][4];
#pragma unroll
  for (int i = 0; i < 4; ++i)
#pragma unroll
    for (int j = 0; j < 4; ++j) acc[i][j] = (f32x4){0.f, 0.f, 0.f, 0.f};

  // prologue: stage 0 and 1
  g2l(Ag, la[0]);      g2l(Ag + 16 * 256, la[0] + 16 * 32);
  g2l(Bg, lb[0]);      g2l(Bg + 16 * 256, lb[0] + 16 * 32);
  g2l(Ag + 32, la[1]); g2l(Ag + 16 * 256 + 32, la[1] + 16 * 32);
  g2l(Bg + 32, lb[1]); g2l(Bg + 16 * 256 + 32, lb[1] + 16 * 32);

#pragma unroll
  for (int k = 0; k < 8; ++k) {
    const int cb = k % 3;
    const int sb = (k + 2) % 3;
    if (k < 7) { asm volatile("s_waitcnt vmcnt(4)" ::: "memory"); }
    else       { asm volatile("s_waitcnt vmcnt(0)" ::: "memory"); }
    __builtin_amdgcn_sched_barrier(0);
    __builtin_amdgcn_s_barrier();
    __builtin_amdgcn_sched_barrier(0);
    if (k + 2 <= 7) {
      int k2 = (k + 2) * 32;
      g2l(Ag + k2, la[sb]); g2l(Ag + 16 * 256 + k2, la[sb] + 16 * 32);
      g2l(Bg + k2, lb[sb]); g2l(Bg + 16 * 256 + k2, lb[sb] + 16 * 32);
    }
    bf16x8 af[4], bfr[4];
#pragma unroll
    for (int mi = 0; mi < 4; ++mi)
      af[mi] = *(const bf16x8*)&As[cb][(wm + mi * 16 + l15) * 32 + pc * 8];
#pragma unroll
    for (int ni = 0; ni < 4; ++ni)
      bfr[ni] = *(const bf16x8*)&Bs[cb][(wn + ni * 16 + l15) * 32 + pc * 8];
#pragma unroll
    for (int mi = 0; mi < 4; ++mi)
#pragma unroll
      for (int ni = 0; ni < 4; ++ni)
        acc[mi][ni] = __builtin_amdgcn_mfma_f32_16x16x32_bf16(af[mi], bfr[ni], acc[mi][ni], 0, 0, 0);
  }

#pragma unroll
  for (int mi = 0; mi < 4; ++mi)
#pragma unroll
    for (int ni = 0; ni < 4; ++ni) {
      int col = bn + wn + ni * 16 + l15;
      float bb = bias[col];
#pragma unroll
      for (int r = 0; r < 4; ++r) {
        int row = bm + wm + mi * 16 + l4 * 4 + r;
        C[(size_t)row * 256 + col] = acc[mi][ni][r] + bb;
      }
    }
}

// ---------------- deformable sampling (v7, unchanged from r11) ----------------
__device__ inline void fmah(float* a, uint4 u, float wv) {
  union { uint4 u; _Float16 h[8]; } c; c.u = u;
#pragma unroll
  for (int i = 0; i < 8; ++i) a[i] = fmaf((float)c.h[i], wv, a[i]);
}

__global__ __launch_bounds__(256) void msda_sample(
    const ushort* __restrict__ val, const float* __restrict__ offlog,
    const float* __restrict__ ref, ushort* __restrict__ interm, int vb0) {
  int vb  = vb0 + blockIdx.x;
  int h   = vb & 7;
  int z   = vb >> 3;                       // 0..1359
  int s   = threadIdx.x & 7;               // sub-lane in 8-lane group
  int o   = s & 3;                         // owned level
  int pp  = s >> 2;                        // owned point-pair (pts 2pp, 2pp+1)
  bool xs = s >= 4;                        // consumed x-side
  int bq  = z * 32 + (threadIdx.x >> 3);   // 1360*32 = 43520
  int b   = (bq >= QN) ? 1 : 0;
  const ushort* vbl = val + (size_t)((uint)(b * 8 + h) * (uint)QN) * 32u + (uint)(s * 8);

  const float* lgp = offlog + (size_t)bq * 384 + 256 + h * 16;
  float2 lg = *(const float2*)(lgp + o * 4 + pp * 2);
  float m = fmaxf(lg.x, lg.y);
  m = fmaxf(m, __shfl_xor(m, 1, 64));
  m = fmaxf(m, __shfl_xor(m, 2, 64));
  m = fmaxf(m, __shfl_xor(m, 4, 64));
  float e0 = __expf(lg.x - m), e1 = __expf(lg.y - m);
  float ssum = e0 + e1;
  ssum += __shfl_xor(ssum, 1, 64);
  ssum += __shfl_xor(ssum, 2, 64);
  ssum += __shfl_xor(ssum, 4, 64);
  float inv = __builtin_amdgcn_rcpf(ssum);
  float aw0 = e0 * inv, aw1 = e1 * inv;

  const int  Wl  = 128 >> o;                       // 128,64,32,16
  const uint t16 = 65536u >> (o + o);
  const int  lst = (int)((65536u - t16) / 3u);     // 0,16384,20480,21504
  const float fW = (float)Wl;
  const float* offp = offlog + (size_t)bq * 384 + h * 32;
  float4 f0 = *(const float4*)(offp + o * 8 + pp * 4);   // ox,oy for 2 pts
  float2 rf = *(const float2*)(ref + (size_t)bq * 8 + o * 2);
  const float xb = rf.x * fW - 0.5f;
  const float yb = rf.y * fW - 0.5f;
  float ox[2] = { f0.x, f0.z };
  float oy[2] = { f0.y, f0.w };
  float awq[2] = { aw0, aw1 };

  uint  pA0[2], pA1[2];
  float pW0[2], pW1[2], pY0[2], pY1[2];
#pragma unroll
  for (int q = 0; q < 2; ++q) {
    float x = xb + ox[q], y = yb + oy[q];
    float x0f = floorf(x), y0f = floorf(y);
    float fx = x - x0f, fy = y - y0f;
    int x0 = (int)x0f, y0 = (int)y0f;
    float a = awq[q];
    float wx0 = ((uint)x0       < (uint)Wl) ? (1.f - fx) : 0.f;
    float wx1 = ((uint)(x0 + 1) < (uint)Wl) ? fx         : 0.f;
    pY0[q] = (((uint)y0       < (uint)Wl) ? (1.f - fy) : 0.f) * a;
    pY1[q] = (((uint)(y0 + 1) < (uint)Wl) ? fy         : 0.f) * a;
    int xc0 = min(max(x0, 0), Wl - 1);
    int xc1 = min(max(x0 + 1, 0), Wl - 1);
    int yc0 = min(max(y0, 0), Wl - 1);
    int yc1 = min(max(y0 + 1, 0), Wl - 1);
    int xbase = min(max(x0, 0), Wl - 2);
    pW0[q] = ((xbase     == xc0) ? wx0 : 0.f) + ((xbase     == xc1) ? wx1 : 0.f);
    pW1[q] = ((xbase + 1 == xc0) ? wx0 : 0.f) + ((xbase + 1 == xc1) ? wx1 : 0.f);
    pA0[q] = (uint)((lst + yc0 * Wl + xbase) * 32);   // elem offset, row y0
    pA1[q] = (uint)((lst + yc1 * Wl + xbase) * 32);   // elem offset, row y1
  }

  float acc[8];
#pragma unroll
  for (int i = 0; i < 8; ++i) acc[i] = 0.f;

  const int gb = (threadIdx.x & 63) & ~7;            // group base lane

  uint  bA0[2], bA1[2];
  float bW[2], bY0[2], bY1[2];
  uint4 u0[2], u1[2];

#define MSDA_BCAST(J, S) do {                                   \
    const int l_ = (J) >> 2, p_ = (J) & 3;                      \
    const int src_ = gb | ((p_ >> 1) << 2) | l_;                \
    const int q_ = p_ & 1;                                      \
    bA0[S] = (uint)__shfl((int)pA0[q_], src_, 64);              \
    bA1[S] = (uint)__shfl((int)pA1[q_], src_, 64);              \
    float w0_ = __shfl(pW0[q_], src_, 64);                      \
    float w1_ = __shfl(pW1[q_], src_, 64);                      \
    bW[S]  = xs ? w1_ : w0_;                                    \
    bY0[S] = __shfl(pY0[q_], src_, 64);                         \
    bY1[S] = __shfl(pY1[q_], src_, 64);                         \
  } while (0)
#define MSDA_LOAD(S) do {                                       \
    u0[S] = *(const uint4*)(vbl + bA0[S]);                      \
    u1[S] = *(const uint4*)(vbl + bA1[S]);                      \
  } while (0)

  MSDA_BCAST(0, 0);
  MSDA_LOAD(0);
#pragma unroll
  for (int j = 0; j < 16; ++j) {
    const int cur = j & 1, nxt = cur ^ 1;
    if (j < 15) { MSDA_BCAST(j + 1, nxt); MSDA_LOAD(nxt); }
    fmah(acc, u0[cur], bW[cur] * bY0[cur]);
    fmah(acc, u1[cur], bW[cur] * bY1[cur]);
  }
#undef MSDA_BCAST
#undef MSDA_LOAD

#pragma unroll
  for (int i = 0; i < 8; ++i) acc[i] += __shfl_xor(acc[i], 4, 64);

  uint2 ov;
  if (!xs) { ov.x = pk2(acc[0], acc[1]); ov.y = pk2(acc[2], acc[3]); }
  else     { ov.x = pk2(acc[4], acc[5]); ov.y = pk2(acc[6], acc[7]); }
  *(uint2*)(interm + (size_t)bq * 256 + h * 32 + (s & 3) * 8 + (xs ? 4 : 0)) = ov;
}

extern "C" void kernel_launch(void* const* d_in, const int* in_sizes, int n_in,
                              void* d_out, int out_size, void* d_ws, size_t ws_size,
                              hipStream_t stream) {
  const float* query = (const float*)d_in[0];
  const float* value = (const float*)d_in[1];
  const float* ref   = (const float*)d_in[2];
  const float* W_off  = (const float*)d_in[4];
  const float* b_off  = (const float*)d_in[5];
  const float* W_attn = (const float*)d_in[6];
  const float* b_attn = (const float*)d_in[7];
  const float* W_v    = (const float*)d_in[8];
  const float* b_v    = (const float*)d_in[9];
  const float* W_out  = (const float*)d_in[10];
  const float* b_out  = (const float*)d_in[11];
  float* out = (float*)d_out;

  // ---- workspace (byte offsets, 256-aligned) ----
  char* wsb = (char*)d_ws;
  ushort* ws_wv     = (ushort*)(wsb + 0);          // 131072 B
  ushort* ws_wol    = (ushort*)(wsb + 131072);     // 196608 B
  ushort* ws_wout   = (ushort*)(wsb + 327680);     // 131072 B
  float*  ws_biasf  = (float*)(wsb + 458752);      // 4096 B
  ushort* ws_val    = (ushort*)(wsb + 462848);     // 22282240 B fp16 head-split
  ushort* ws_interm = (ushort*)(wsb + 22745088);   // 22282240 B bf16 (M,256)
  float*  ws_offlog = (float*)(wsb + 45027328);    // 66846720 B f32 (M,384)
  size_t need = (size_t)45027328 + 66846720;       // ~112 MB
  if (ws_size < need) return;

  dim3 blk(256);
  prep_weights<<<dim3(896), blk, 0, stream>>>(W_v, W_out, W_off, W_attn, b_off, b_attn,
                                              ws_wv, ws_wout, ws_wol, ws_biasf);
  // split kept for per-kernel visibility (A/B vs r11's 44.2/43.6 us)
  gemm_in<<<dim3(340, 2), blk, 0, stream>>>(value, query, ws_wv, ws_wol, b_v, ws_biasf,
                                            ws_val, ws_offlog, 0);
  gemm_in<<<dim3(340, 3), blk, 0, stream>>>(value, query, ws_wv, ws_wol, b_v, ws_biasf,
                                            ws_val, ws_offlog, 2);
  msda_sample<<<dim3(2720), blk, 0, stream>>>(ws_val, ws_offlog, ref, ws_interm, 0);
  msda_sample<<<dim3(2720), blk, 0, stream>>>(ws_val, ws_offlog, ref, ws_interm, 2720);
  msda_sample<<<dim3(2720), blk, 0, stream>>>(ws_val, ws_offlog, ref, ws_interm, 5440);
  msda_sample<<<dim3(2720), blk, 0, stream>>>(ws_val, ws_offlog, ref, ws_interm, 8160);
  gemm_out<<<dim3(340, 2), blk, 0, stream>>>(ws_interm, ws_wout, b_out, out);
}

// Round 13
// 269.505 us; speedup vs baseline: 1.0634x; 1.0438x over previous
//
#include <hip/hip_runtime.h>
#include <math.h>

#define QN 21760
#define MTOT 43520      // = 340 * 128
#define SZBQC 11141120  // MTOT*256

typedef __attribute__((ext_vector_type(8))) short bf16x8;
typedef __attribute__((ext_vector_type(4))) float f32x4;

__device__ inline ushort f2bf(float f) {
  union { float f; uint u; } v; v.f = f;
  return (ushort)((v.u + 0x7FFFu + ((v.u >> 16) & 1u)) >> 16);
}
__device__ inline uint pk2(float lo, float hi) { return (uint)f2bf(lo) | ((uint)f2bf(hi) << 16); }

__device__ inline void g2l(const ushort* g, ushort* l) {
  __builtin_amdgcn_global_load_lds(
      (const __attribute__((address_space(1))) void*)g,
      (__attribute__((address_space(3))) void*)l, 16, 0, 0);
}

// ---------------- weight prep ----------------
__global__ __launch_bounds__(256) void prep_weights(
    const float* __restrict__ Wv, const float* __restrict__ Wout,
    const float* __restrict__ Woff, const float* __restrict__ Wattn,
    const float* __restrict__ boff, const float* __restrict__ battn,
    ushort* __restrict__ wv_t, ushort* __restrict__ wout_t,
    ushort* __restrict__ wol_t, float* __restrict__ biasf) {
  int bidx = blockIdx.x, t = threadIdx.x;
  if (bidx < 256) {
    int idx = bidx * 256 + t; int n = idx >> 8, k = idx & 255;
    wv_t[idx] = f2bf(Wv[(size_t)k * 256 + n]);
  } else if (bidx < 512) {
    int idx = (bidx - 256) * 256 + t; int n = idx >> 8, k = idx & 255;
    wout_t[idx] = f2bf(Wout[(size_t)k * 256 + n]);
  } else {
    int idx = (bidx - 512) * 256 + t; int n = idx >> 8, k = idx & 255;
    float v = (n < 256) ? Woff[(size_t)k * 256 + n] : Wattn[(size_t)k * 128 + (n - 256)];
    wol_t[idx] = f2bf(v);
    if (idx < 384) biasf[idx] = (idx < 256) ? boff[idx] : battn[idx - 256];
  }
}

// ---- XOR-swizzled LDS tile: 128 rows x 32 ushort; 16B chunk c of row r
// lives at physical chunk c ^ ((r>>1)&3). Frag reads are conflict-free. ----

// ---------------- panel-merged input GEMM ----------------
// grid (340, 2): y=0 -> A=value, panels 0-1 (val);  y=1 -> A=query,
// panels 2-4 (offlog). A tile is cast f32->bf16 ONCE into LDS k-major
// AsF[8][128x32], then all panels reuse it (A HBM reads 223->89 MB, cast
// VALU /2.5). B per k-step dbuf-staged via g2l (r6-proven sync pattern).
// LDS 80 KB -> 2 blocks/CU.
__global__ __launch_bounds__(256) void gemm_in(
    const float* __restrict__ value, const float* __restrict__ query,
    const ushort* __restrict__ Wv, const ushort* __restrict__ Wol,
    const float* __restrict__ bv, const float* __restrict__ bol,
    ushort* __restrict__ val_out, float* __restrict__ offlog) {
  __shared__ ushort AsF[8][4096];
  __shared__ ushort Bs[2][4096];
  const int t = threadIdx.x, wave = t >> 6, lane = t & 63;
  const int grp = blockIdx.y;               // 0: val, 1: offlog
  const int bm = blockIdx.x * 128;
  const float* A = grp ? query : value;
  const int npan = grp ? 3 : 2;
  const int wm = (wave >> 1) * 64, wn = (wave & 1) * 64;
  const int l15 = lane & 15, l4 = lane >> 4;
  const int pc = l4 ^ ((l15 >> 1) & 3);     // frag-read physical chunk

  const int srow = lane >> 2;
  const int sch  = (lane & 3) ^ ((lane >> 3) & 3);
  const ushort* Bgbase = (grp ? Wol : Wv) + (size_t)(32 * wave + srow) * 256 + sch * 8;
  ushort* lb[2] = { &Bs[0][(32 * wave) * 32], &Bs[1][(32 * wave) * 32] };

  int arow[4], apart[4];
#pragma unroll
  for (int i = 0; i < 4; ++i) {
    int c = t + i * 256; arow[i] = c >> 3; apart[i] = c & 7;
  }

  // prefetch panel-0 B k=0 while A staging runs
  g2l(Bgbase, lb[0]); g2l(Bgbase + 16 * 256, lb[0] + 16 * 32);

  // stage FULL A tile once: cast f32->bf16, k-major swizzled layout
#pragma unroll
  for (int k = 0; k < 8; ++k) {
    float4 pa[4];
#pragma unroll
    for (int i = 0; i < 4; ++i)
      pa[i] = *(const float4*)&A[(size_t)(bm + arow[i]) * 256 + k * 32 + apart[i] * 4];
#pragma unroll
    for (int i = 0; i < 4; ++i) {
      int pc16 = (apart[i] >> 1) ^ ((arow[i] >> 1) & 3);
      ushort4 hv = { f2bf(pa[i].x), f2bf(pa[i].y), f2bf(pa[i].z), f2bf(pa[i].w) };
      *(ushort4*)&AsF[k][arow[i] * 32 + pc16 * 8 + (apart[i] & 1) * 4] = hv;
    }
  }

  for (int p = 0; p < npan; ++p) {
    const ushort* Bg = Bgbase + (size_t)p * 32768;
    if (p > 0) {
      // WAR-safe: lb[0] last read at k=6 of panel p-1; all waves passed the
      // k=7 barrier (which followed those reads) before reaching here.
      g2l(Bg, lb[0]); g2l(Bg + 16 * 256, lb[0] + 16 * 32);
    }

    f32x4 acc[4][4];
#pragma unroll
    for (int i = 0; i < 4; ++i)
#pragma unroll
      for (int j = 0; j < 4; ++j) acc[i][j] = (f32x4){0.f, 0.f, 0.f, 0.f};

#pragma unroll
    for (int k = 0; k < 8; ++k) {
      __syncthreads();   // drains this wave's g2l (vmcnt) + A ds_writes (lgkm)
      const int cur = k & 1, nxt = cur ^ 1;
      if (k < 7) {
        int k1 = (k + 1) * 32;
        g2l(Bg + k1, lb[nxt]); g2l(Bg + 16 * 256 + k1, lb[nxt] + 16 * 32);
      }
      bf16x8 af[4], bfr[4];
#pragma unroll
      for (int mi = 0; mi < 4; ++mi)
        af[mi] = *(const bf16x8*)&AsF[k][(wm + mi * 16 + l15) * 32 + pc * 8];
#pragma unroll
      for (int ni = 0; ni < 4; ++ni)
        bfr[ni] = *(const bf16x8*)&Bs[cur][(wn + ni * 16 + l15) * 32 + pc * 8];
#pragma unroll
      for (int mi = 0; mi < 4; ++mi)
#pragma unroll
        for (int ni = 0; ni < 4; ++ni)
          acc[mi][ni] = __builtin_amdgcn_mfma_f32_16x16x32_bf16(af[mi], bfr[ni], acc[mi][ni], 0, 0, 0);
    }

    const int bx = grp ? (2 + p) : p;
    if (bx < 2) {
      _Float16* vo = (_Float16*)val_out;
#pragma unroll
      for (int mi = 0; mi < 4; ++mi)
#pragma unroll
        for (int ni = 0; ni < 4; ++ni) {
          int col = bx * 128 + wn + ni * 16 + l15;
          float bb = bv[col];
          int hh = col >> 5, c = col & 31;
#pragma unroll
          for (int r = 0; r < 4; ++r) {
            int row = bm + wm + mi * 16 + l4 * 4 + r;
            int b = (row >= QN) ? 1 : 0;
            int vpos = row - b * QN;
            vo[((size_t)(b * 8 + hh) * QN + vpos) * 32 + c] = (_Float16)(acc[mi][ni][r] + bb);
          }
        }
    } else {
#pragma unroll
      for (int mi = 0; mi < 4; ++mi)
#pragma unroll
        for (int ni = 0; ni < 4; ++ni) {
          int col = (bx - 2) * 128 + wn + ni * 16 + l15;
          float bb = bol[col];
#pragma unroll
          for (int r = 0; r < 4; ++r) {
            int row = bm + wm + mi * 16 + l4 * 4 + r;
            offlog[(size_t)row * 384 + col] = acc[mi][ni][r] + bb;
          }
        }
    }
  }
}

// ---------------- output GEMM — counted-vmcnt, raw-barrier, 3-buf (r12) ----
__global__ __launch_bounds__(256) void gemm_out(
    const ushort* __restrict__ A, const ushort* __restrict__ Bt,
    const float* __restrict__ bias, float* __restrict__ C) {
  __shared__ ushort As[3][4096];
  __shared__ ushort Bs[3][4096];
  const int t = threadIdx.x, wave = t >> 6, lane = t & 63;
  const int bm = blockIdx.x * 128, bn = blockIdx.y * 128;
  const int wm = (wave >> 1) * 64, wn = (wave & 1) * 64;
  const int l15 = lane & 15, l4 = lane >> 4;
  const int pc = l4 ^ ((l15 >> 1) & 3);

  const int srow = lane >> 2;
  const int sch  = (lane & 3) ^ ((lane >> 3) & 3);
  const ushort* Ag = A + (size_t)(bm + 32 * wave + srow) * 256 + sch * 8;
  const ushort* Bg = Bt + (size_t)(bn + 32 * wave + srow) * 256 + sch * 8;
  ushort* la[3] = { &As[0][(32 * wave) * 32], &As[1][(32 * wave) * 32],
                    &As[2][(32 * wave) * 32] };
  ushort* lb[3] = { &Bs[0][(32 * wave) * 32], &Bs[1][(32 * wave) * 32],
                    &Bs[2][(32 * wave) * 32] };

  f32x4 acc[4][4];
#pragma unroll
  for (int i = 0; i < 4; ++i)
#pragma unroll
    for (int j = 0; j < 4; ++j) acc[i][j] = (f32x4){0.f, 0.f, 0.f, 0.f};

  g2l(Ag, la[0]);      g2l(Ag + 16 * 256, la[0] + 16 * 32);
  g2l(Bg, lb[0]);      g2l(Bg + 16 * 256, lb[0] + 16 * 32);
  g2l(Ag + 32, la[1]); g2l(Ag + 16 * 256 + 32, la[1] + 16 * 32);
  g2l(Bg + 32, lb[1]); g2l(Bg + 16 * 256 + 32, lb[1] + 16 * 32);

#pragma unroll
  for (int k = 0; k < 8; ++k) {
    const int cb = k % 3;
    const int sb = (k + 2) % 3;
    if (k < 7) { asm volatile("s_waitcnt vmcnt(4)" ::: "memory"); }
    else       { asm volatile("s_waitcnt vmcnt(0)" ::: "memory"); }
    __builtin_amdgcn_sched_barrier(0);
    __builtin_amdgcn_s_barrier();
    __builtin_amdgcn_sched_barrier(0);
    if (k + 2 <= 7) {
      int k2 = (k + 2) * 32;
      g2l(Ag + k2, la[sb]); g2l(Ag + 16 * 256 + k2, la[sb] + 16 * 32);
      g2l(Bg + k2, lb[sb]); g2l(Bg + 16 * 256 + k2, lb[sb] + 16 * 32);
    }
    bf16x8 af[4], bfr[4];
#pragma unroll
    for (int mi = 0; mi < 4; ++mi)
      af[mi] = *(const bf16x8*)&As[cb][(wm + mi * 16 + l15) * 32 + pc * 8];
#pragma unroll
    for (int ni = 0; ni < 4; ++ni)
      bfr[ni] = *(const bf16x8*)&Bs[cb][(wn + ni * 16 + l15) * 32 + pc * 8];
#pragma unroll
    for (int mi = 0; mi < 4; ++mi)
#pragma unroll
      for (int ni = 0; ni < 4; ++ni)
        acc[mi][ni] = __builtin_amdgcn_mfma_f32_16x16x32_bf16(af[mi], bfr[ni], acc[mi][ni], 0, 0, 0);
  }

#pragma unroll
  for (int mi = 0; mi < 4; ++mi)
#pragma unroll
    for (int ni = 0; ni < 4; ++ni) {
      int col = bn + wn + ni * 16 + l15;
      float bb = bias[col];
#pragma unroll
      for (int r = 0; r < 4; ++r) {
        int row = bm + wm + mi * 16 + l4 * 4 + r;
        C[(size_t)row * 256 + col] = acc[mi][ni][r] + bb;
      }
    }
}

// ---------------- deformable sampling (v7, single dispatch again) ----------------
__device__ inline void fmah(float* a, uint4 u, float wv) {
  union { uint4 u; _Float16 h[8]; } c; c.u = u;
#pragma unroll
  for (int i = 0; i < 8; ++i) a[i] = fmaf((float)c.h[i], wv, a[i]);
}

__global__ __launch_bounds__(256) void msda_sample(
    const ushort* __restrict__ val, const float* __restrict__ offlog,
    const float* __restrict__ ref, ushort* __restrict__ interm) {
  int vb  = blockIdx.x;
  int h   = vb & 7;
  int z   = vb >> 3;                       // 0..1359
  int s   = threadIdx.x & 7;               // sub-lane in 8-lane group
  int o   = s & 3;                         // owned level
  int pp  = s >> 2;                        // owned point-pair (pts 2pp, 2pp+1)
  bool xs = s >= 4;                        // consumed x-side
  int bq  = z * 32 + (threadIdx.x >> 3);   // 1360*32 = 43520
  int b   = (bq >= QN) ? 1 : 0;
  const ushort* vbl = val + (size_t)((uint)(b * 8 + h) * (uint)QN) * 32u + (uint)(s * 8);

  const float* lgp = offlog + (size_t)bq * 384 + 256 + h * 16;
  float2 lg = *(const float2*)(lgp + o * 4 + pp * 2);
  float m = fmaxf(lg.x, lg.y);
  m = fmaxf(m, __shfl_xor(m, 1, 64));
  m = fmaxf(m, __shfl_xor(m, 2, 64));
  m = fmaxf(m, __shfl_xor(m, 4, 64));
  float e0 = __expf(lg.x - m), e1 = __expf(lg.y - m);
  float ssum = e0 + e1;
  ssum += __shfl_xor(ssum, 1, 64);
  ssum += __shfl_xor(ssum, 2, 64);
  ssum += __shfl_xor(ssum, 4, 64);
  float inv = __builtin_amdgcn_rcpf(ssum);
  float aw0 = e0 * inv, aw1 = e1 * inv;

  const int  Wl  = 128 >> o;                       // 128,64,32,16
  const uint t16 = 65536u >> (o + o);
  const int  lst = (int)((65536u - t16) / 3u);     // 0,16384,20480,21504
  const float fW = (float)Wl;
  const float* offp = offlog + (size_t)bq * 384 + h * 32;
  float4 f0 = *(const float4*)(offp + o * 8 + pp * 4);   // ox,oy for 2 pts
  float2 rf = *(const float2*)(ref + (size_t)bq * 8 + o * 2);
  const float xb = rf.x * fW - 0.5f;
  const float yb = rf.y * fW - 0.5f;
  float ox[2] = { f0.x, f0.z };
  float oy[2] = { f0.y, f0.w };
  float awq[2] = { aw0, aw1 };

  uint  pA0[2], pA1[2];
  float pW0[2], pW1[2], pY0[2], pY1[2];
#pragma unroll
  for (int q = 0; q < 2; ++q) {
    float x = xb + ox[q], y = yb + oy[q];
    float x0f = floorf(x), y0f = floorf(y);
    float fx = x - x0f, fy = y - y0f;
    int x0 = (int)x0f, y0 = (int)y0f;
    float a = awq[q];
    float wx0 = ((uint)x0       < (uint)Wl) ? (1.f - fx) : 0.f;
    float wx1 = ((uint)(x0 + 1) < (uint)Wl) ? fx         : 0.f;
    pY0[q] = (((uint)y0       < (uint)Wl) ? (1.f - fy) : 0.f) * a;
    pY1[q] = (((uint)(y0 + 1) < (uint)Wl) ? fy         : 0.f) * a;
    int xc0 = min(max(x0, 0), Wl - 1);
    int xc1 = min(max(x0 + 1, 0), Wl - 1);
    int yc0 = min(max(y0, 0), Wl - 1);
    int yc1 = min(max(y0 + 1, 0), Wl - 1);
    int xbase = min(max(x0, 0), Wl - 2);
    pW0[q] = ((xbase     == xc0) ? wx0 : 0.f) + ((xbase     == xc1) ? wx1 : 0.f);
    pW1[q] = ((xbase + 1 == xc0) ? wx0 : 0.f) + ((xbase + 1 == xc1) ? wx1 : 0.f);
    pA0[q] = (uint)((lst + yc0 * Wl + xbase) * 32);   // elem offset, row y0
    pA1[q] = (uint)((lst + yc1 * Wl + xbase) * 32);   // elem offset, row y1
  }

  float acc[8];
#pragma unroll
  for (int i = 0; i < 8; ++i) acc[i] = 0.f;

  const int gb = (threadIdx.x & 63) & ~7;            // group base lane

  uint  bA0[2], bA1[2];
  float bW[2], bY0[2], bY1[2];
  uint4 u0[2], u1[2];

#define MSDA_BCAST(J, S) do {                                   \
    const int l_ = (J) >> 2, p_ = (J) & 3;                      \
    const int src_ = gb | ((p_ >> 1) << 2) | l_;                \
    const int q_ = p_ & 1;                                      \
    bA0[S] = (uint)__shfl((int)pA0[q_], src_, 64);              \
    bA1[S] = (uint)__shfl((int)pA1[q_], src_, 64);              \
    float w0_ = __shfl(pW0[q_], src_, 64);                      \
    float w1_ = __shfl(pW1[q_], src_, 64);                      \
    bW[S]  = xs ? w1_ : w0_;                                    \
    bY0[S] = __shfl(pY0[q_], src_, 64);                         \
    bY1[S] = __shfl(pY1[q_], src_, 64);                         \
  } while (0)
#define MSDA_LOAD(S) do {                                       \
    u0[S] = *(const uint4*)(vbl + bA0[S]);                      \
    u1[S] = *(const uint4*)(vbl + bA1[S]);                      \
  } while (0)

  MSDA_BCAST(0, 0);
  MSDA_LOAD(0);
#pragma unroll
  for (int j = 0; j < 16; ++j) {
    const int cur = j & 1, nxt = cur ^ 1;
    if (j < 15) { MSDA_BCAST(j + 1, nxt); MSDA_LOAD(nxt); }
    fmah(acc, u0[cur], bW[cur] * bY0[cur]);
    fmah(acc, u1[cur], bW[cur] * bY1[cur]);
  }
#undef MSDA_BCAST
#undef MSDA_LOAD

#pragma unroll
  for (int i = 0; i < 8; ++i) acc[i] += __shfl_xor(acc[i], 4, 64);

  uint2 ov;
  if (!xs) { ov.x = pk2(acc[0], acc[1]); ov.y = pk2(acc[2], acc[3]); }
  else     { ov.x = pk2(acc[4], acc[5]); ov.y = pk2(acc[6], acc[7]); }
  *(uint2*)(interm + (size_t)bq * 256 + h * 32 + (s & 3) * 8 + (xs ? 4 : 0)) = ov;
}

extern "C" void kernel_launch(void* const* d_in, const int* in_sizes, int n_in,
                              void* d_out, int out_size, void* d_ws, size_t ws_size,
                              hipStream_t stream) {
  const float* query = (const float*)d_in[0];
  const float* value = (const float*)d_in[1];
  const float* ref   = (const float*)d_in[2];
  const float* W_off  = (const float*)d_in[4];
  const float* b_off  = (const float*)d_in[5];
  const float* W_attn = (const float*)d_in[6];
  const float* b_attn = (const float*)d_in[7];
  const float* W_v    = (const float*)d_in[8];
  const float* b_v    = (const float*)d_in[9];
  const float* W_out  = (const float*)d_in[10];
  const float* b_out  = (const float*)d_in[11];
  float* out = (float*)d_out;

  // ---- workspace (byte offsets, 256-aligned) ----
  char* wsb = (char*)d_ws;
  ushort* ws_wv     = (ushort*)(wsb + 0);          // 131072 B
  ushort* ws_wol    = (ushort*)(wsb + 131072);     // 196608 B
  ushort* ws_wout   = (ushort*)(wsb + 327680);     // 131072 B
  float*  ws_biasf  = (float*)(wsb + 458752);      // 4096 B
  ushort* ws_val    = (ushort*)(wsb + 462848);     // 22282240 B fp16 head-split
  ushort* ws_interm = (ushort*)(wsb + 22745088);   // 22282240 B bf16 (M,256)
  float*  ws_offlog = (float*)(wsb + 45027328);    // 66846720 B f32 (M,384)
  size_t need = (size_t)45027328 + 66846720;       // ~112 MB
  if (ws_size < need) return;

  dim3 blk(256);
  prep_weights<<<dim3(896), blk, 0, stream>>>(W_v, W_out, W_off, W_attn, b_off, b_attn,
                                              ws_wv, ws_wout, ws_wol, ws_biasf);
  gemm_in<<<dim3(340, 2), blk, 0, stream>>>(value, query, ws_wv, ws_wol, b_v, ws_biasf,
                                            ws_val, ws_offlog);
  msda_sample<<<dim3(10880), blk, 0, stream>>>(ws_val, ws_offlog, ref, ws_interm);
  gemm_out<<<dim3(340, 2), blk, 0, stream>>>(ws_interm, ws_wout, b_out, out);
}